// Round 17
// baseline (501.582 us; speedup 1.0000x reference)
//
#include <hip/hip_runtime.h>
#include <stdint.h>
#include <stddef.h>

#define N_PTS 262144
#define M_PTS 131072
#define C_DIM 256
#define H_DIM 32
#define EPS_BN 1e-5f
#define NSLOT_A 64
#define NSLOT_B 16
#define NSLOT_T 64

using s16x8 = __attribute__((ext_vector_type(8))) short;
using s16x4 = __attribute__((ext_vector_type(4))) short;
using f32x4 = __attribute__((ext_vector_type(4))) float;

__device__ __forceinline__ short f2bf(float f) {
  __bf16 h = (__bf16)f;
  return __builtin_bit_cast(short, h);
}
__device__ __forceinline__ float bf2f(short s) {
  unsigned int u = ((unsigned int)(unsigned short)s) << 16;
  return __builtin_bit_cast(float, u);
}
__device__ __forceinline__ f32x4 mfma16(s16x8 a, s16x8 b, f32x4 c) {
  return __builtin_amdgcn_mfma_f32_16x16x32_bf16(a, b, c, 0, 0, 0);
}
__device__ __forceinline__ f32x4 nt_load_f4(const float* p) {
  return __builtin_nontemporal_load((const f32x4*)p);
}
__device__ __forceinline__ s16x8 nt_load_s8(const short* p) {
  return __builtin_nontemporal_load((const s16x8*)p);
}

// ---------------- k_init: zero stats, convert weights to bf16 (1 launch) ----------------
__global__ __launch_bounds__(256) void k_init(
    float* __restrict__ wsf, float* __restrict__ sum_t,
    const float* __restrict__ W1, const float* __restrict__ W2,
    const float* __restrict__ Wlin) {
  int t = threadIdx.x, b = blockIdx.x;
  f32x4 z = {0.f, 0.f, 0.f, 0.f};
  if (b == 0) {
    *(f32x4*)(wsf + t * 4) = z;                 // sum_b (1024 floats)
  } else if (b <= 64) {
    *(f32x4*)(sum_t + (size_t)((b - 1) * 256 + t) * 4) = z;  // sum_t|sum_a (65536)
  } else {
    int i = (b - 65) * 256 + t;                 // 81920 prep threads
    short* W1b  = (short*)(wsf + 2112);
    short* W2b  = (short*)(wsf + 6208);
    short* Wlb2 = (short*)(wsf + 10304);
    if (i < 8192) {
      W1b[i] = f2bf(W1[i]);
    } else if (i < 16384) {
      W2b[i - 8192] = f2bf(W2[i - 8192]);
    } else {
      int s = i - 16384;
      int col = s >> 8, k = s & 255;
      int ksl = k >> 5, kg = (k >> 3) & 3, e = k & 7;
      int n = col >> 4, cl = col & 15;
      Wlb2[ksl * 8192 + n * 512 + kg * 128 + cl * 8 + e] = f2bf(Wlin[s]);
    }
  }
}

// ---------------- k_rel: rel = x - gx[idx] (bf16, 16B stores) + BN_a stats ----------------
__global__ __launch_bounds__(256) void k_rel(
    const float* __restrict__ x, const float* __restrict__ gx,
    const int* __restrict__ idx, short* __restrict__ rel,
    float* __restrict__ sum_a) {
  __shared__ int lidx[64];
  __shared__ float redS[8][264];
  __shared__ float redQ[8][264];
  int t = threadIdx.x;
  int rg = t >> 5;          // row-group 0..7 (8 rows per iteration)
  int c8 = (t & 31) * 8;    // column start (8 floats/shorts per lane)
  int brow = blockIdx.x * 64;
  if (t < 64) lidx[t] = idx[brow + t];
  __syncthreads();

  float s[8] = {0, 0, 0, 0, 0, 0, 0, 0};
  float q[8] = {0, 0, 0, 0, 0, 0, 0, 0};
#pragma unroll 4
  for (int it = 0; it < 8; ++it) {
    int rl = it * 8 + rg;
    int ir = lidx[rl];
    const float* xr = x + (size_t)(brow + rl) * 256 + c8;
    const float* gr = gx + (size_t)ir * 256 + c8;
    f32x4 xa = nt_load_f4(xr);
    f32x4 xb = nt_load_f4(xr + 4);
    float4 ga = *(const float4*)(gr);
    float4 gb = *(const float4*)(gr + 4);
    float d0 = xa[0] - ga.x, d1 = xa[1] - ga.y, d2 = xa[2] - ga.z, d3 = xa[3] - ga.w;
    float d4 = xb[0] - gb.x, d5 = xb[1] - gb.y, d6 = xb[2] - gb.z, d7 = xb[3] - gb.w;
    s16x8 h;
    h[0] = f2bf(d0); h[1] = f2bf(d1); h[2] = f2bf(d2); h[3] = f2bf(d3);
    h[4] = f2bf(d4); h[5] = f2bf(d5); h[6] = f2bf(d6); h[7] = f2bf(d7);
    *(s16x8*)(rel + (size_t)(brow + rl) * 256 + c8) = h;
    s[0] += d0; s[1] += d1; s[2] += d2; s[3] += d3;
    s[4] += d4; s[5] += d5; s[6] += d6; s[7] += d7;
    q[0] += d0 * d0; q[1] += d1 * d1; q[2] += d2 * d2; q[3] += d3 * d3;
    q[4] += d4 * d4; q[5] += d5 * d5; q[6] += d6 * d6; q[7] += d7 * d7;
  }
#pragma unroll
  for (int j = 0; j < 8; ++j) {
    redS[rg][c8 + j] = s[j];
    redQ[rg][c8 + j] = q[j];
  }
  __syncthreads();
  float vs = 0.f, vq = 0.f;
#pragma unroll
  for (int g = 0; g < 8; ++g) {
    vs += redS[g][t];
    vq += redQ[g][t];
  }
  float* slot = sum_a + (size_t)(blockIdx.x & (NSLOT_A - 1)) * 512;
  atomicAdd(&slot[t], vs);
  atomicAdd(&slot[256 + t], vq);
}

// ---------------- k_fin: slotted sums -> scale/shift ----------------
__global__ void k_fin(const float* __restrict__ sums, const float* __restrict__ g,
                      const float* __restrict__ b, float* __restrict__ sc,
                      float* __restrict__ sh, int n, float invN, int nslot) {
  int c = threadIdx.x;
  if (c < n) {
    float S = 0.f, Q = 0.f;
    for (int s = 0; s < nslot; ++s) {
      S += sums[(size_t)s * 2 * n + c];
      Q += sums[(size_t)s * 2 * n + n + c];
    }
    float mu = S * invN;
    float var = Q * invN - mu * mu;
    float rs = rsqrtf(var + EPS_BN);
    float scale = g[c] * rs;
    sc[c] = scale;
    sh[c] = b[c] - mu * scale;
  }
}

// ---------------- k_y: y = relu(BN_a(rel)) @ W1^T ; y bf16 + stats ----------------
__global__ __launch_bounds__(256) void k_y(
    const short* __restrict__ rel, const short* __restrict__ W1b,
    const float* __restrict__ sc_a, const float* __restrict__ sh_a,
    short* __restrict__ yh, float* __restrict__ sum_b) {
  __shared__ __attribute__((aligned(16))) short Ab[64 * 264];
  __shared__ float lsc[256];
  __shared__ float lsh[256];
  __shared__ float red[4][64];
  int t = threadIdx.x;
  lsc[t] = sc_a[t];
  lsh[t] = sh_a[t];
  {
    int srow = t >> 2, sseg = (t & 3) * 64;
    const short* src = rel + (size_t)(blockIdx.x * 64 + srow) * 256 + sseg;
    short* dst = Ab + srow * 264 + sseg;
#pragma unroll
    for (int j = 0; j < 8; ++j)
      *(s16x8*)(dst + j * 8) = *(const s16x8*)(src + j * 8);
  }
  __syncthreads();
  int w = t >> 6, l = t & 63, l15 = l & 15, kg = l >> 4;
  int r0 = blockIdx.x * 64 + w * 16;
  const short* arow = Ab + (w * 16 + l15) * 264;

  s16x8 bfr[2][8];
#pragma unroll
  for (int j = 0; j < 2; ++j)
#pragma unroll
    for (int kk = 0; kk < 8; ++kk)
      bfr[j][kk] = *(const s16x8*)(W1b + (j * 16 + l15) * 256 + kg * 8 + kk * 32);

  f32x4 acc0 = {0.f, 0.f, 0.f, 0.f};
  f32x4 acc1 = {0.f, 0.f, 0.f, 0.f};
#pragma unroll
  for (int kk = 0; kk < 8; ++kk) {
    int k0 = kg * 8 + kk * 32;
    s16x8 a = *(const s16x8*)(arow + k0);
    s16x8 af;
#pragma unroll
    for (int i = 0; i < 8; ++i) {
      float v = bf2f(a[i]);
      v = fmaxf(v * lsc[k0 + i] + lsh[k0 + i], 0.f);
      af[i] = f2bf(v);
    }
    acc0 = mfma16(af, bfr[0][kk], acc0);
    acc1 = mfma16(af, bfr[1][kk], acc1);
  }

  float s0 = 0.f, q0 = 0.f, s1 = 0.f, q1 = 0.f;
#pragma unroll
  for (int reg = 0; reg < 4; ++reg) {
    int gr = r0 + kg * 4 + reg;
    float y0 = acc0[reg], y1 = acc1[reg];
    yh[(size_t)gr * 32 + l15] = f2bf(y0);
    yh[(size_t)gr * 32 + 16 + l15] = f2bf(y1);
    s0 += y0; q0 += y0 * y0;
    s1 += y1; q1 += y1 * y1;
  }
  s0 += __shfl_xor(s0, 16); s0 += __shfl_xor(s0, 32);
  q0 += __shfl_xor(q0, 16); q0 += __shfl_xor(q0, 32);
  s1 += __shfl_xor(s1, 16); s1 += __shfl_xor(s1, 32);
  q1 += __shfl_xor(q1, 16); q1 += __shfl_xor(q1, 32);
  if (l < 16) {
    red[w][l15] = s0;
    red[w][16 + l15] = s1;
    red[w][32 + l15] = q0;
    red[w][48 + l15] = q1;
  }
  __syncthreads();
  if (t < 64) {
    float v = red[0][t] + red[1][t] + red[2][t] + red[3][t];
    atomicAdd(&sum_b[(size_t)(blockIdx.x & (NSLOT_B - 1)) * 64 + t], v);
  }
}

// ---------------- k_x2g: z GEMM + softmax + combine + Wlin GEMM ----------------
// Phase 2 now 16B/lane (32 lanes per row, 8 rows/iter). Phase 3 wave-per-column.
__global__ __launch_bounds__(256) void k_x2g(
    const short* __restrict__ yh, const short* __restrict__ W2b,
    const float* __restrict__ b2, const float* __restrict__ x,
    const short* __restrict__ Wlb2, const float* __restrict__ sc_b,
    const float* __restrict__ sh_b, short* __restrict__ big,
    float* __restrict__ sum_t) {
  __shared__ __attribute__((aligned(16))) short swl[64 * 264];  // 33792 B
  __shared__ float ls[512];                                     // 2048 B
  int t = threadIdx.x, w = t >> 6, l = t & 63, l15 = l & 15, kg = l >> 4;
  int r0 = blockIdx.x * 64 + w * 16;
  int lr = r0 + l15;

  // ---- phase 1: z = relu(BN_b(y)) @ W2^T + b2 ; row-softmax -> sw (LDS bf16) ----
  s16x8 yb = *(const s16x8*)(yh + (size_t)lr * 32 + kg * 8);
  s16x8 af;
#pragma unroll
  for (int i = 0; i < 8; ++i) {
    int k = kg * 8 + i;
    float v = bf2f(yb[i]);
    v = fmaxf(v * sc_b[k] + sh_b[k], 0.f);
    af[i] = f2bf(v);
  }
  f32x4 zero = {0.f, 0.f, 0.f, 0.f};
  f32x4 z[16];
#pragma unroll
  for (int n = 0; n < 16; ++n) {
    s16x8 bf = *(const s16x8*)(W2b + (n * 16 + l15) * 32 + kg * 8);
    z[n] = mfma16(af, bf, zero);
  }
  float b2c[16];
#pragma unroll
  for (int n = 0; n < 16; ++n) b2c[n] = b2[n * 16 + l15];
  float mx[4] = {-3.4e38f, -3.4e38f, -3.4e38f, -3.4e38f};
#pragma unroll
  for (int n = 0; n < 16; ++n)
#pragma unroll
    for (int r = 0; r < 4; ++r) {
      z[n][r] += b2c[n];
      mx[r] = fmaxf(mx[r], z[n][r]);
    }
#pragma unroll
  for (int r = 0; r < 4; ++r) {
    mx[r] = fmaxf(mx[r], __shfl_xor(mx[r], 1));
    mx[r] = fmaxf(mx[r], __shfl_xor(mx[r], 2));
    mx[r] = fmaxf(mx[r], __shfl_xor(mx[r], 4));
    mx[r] = fmaxf(mx[r], __shfl_xor(mx[r], 8));
  }
  float sm[4] = {0.f, 0.f, 0.f, 0.f};
#pragma unroll
  for (int n = 0; n < 16; ++n)
#pragma unroll
    for (int r = 0; r < 4; ++r) {
      float e = __expf(z[n][r] - mx[r]);
      z[n][r] = e;
      sm[r] += e;
    }
#pragma unroll
  for (int r = 0; r < 4; ++r) {
    sm[r] += __shfl_xor(sm[r], 1);
    sm[r] += __shfl_xor(sm[r], 2);
    sm[r] += __shfl_xor(sm[r], 4);
    sm[r] += __shfl_xor(sm[r], 8);
    sm[r] = 1.f / sm[r];
  }
#pragma unroll
  for (int n = 0; n < 16; ++n)
#pragma unroll
    for (int r = 0; r < 4; ++r)
      swl[(w * 16 + kg * 4 + r) * 264 + n * 16 + l15] = f2bf(z[n][r] * sm[r]);
  __syncthreads();

  // ---- early-issue B fragments for ksl=0 (latency hides under phase 2) ----
  s16x8 bf0[4], bf1[4];
#pragma unroll
  for (int np = 0; np < 4; ++np)
    bf0[np] = *(const s16x8*)(Wlb2 + (w * 4 + np) * 512 + l * 8);

  // ---- phase 2 (16B/lane): combine in place: swl[row][col] <- x2 = x + sw*(x - rel) ----
  int brow0 = blockIdx.x * 64;
  int rg2 = t >> 5;          // row-group 0..7
  int c8 = (t & 31) * 8;     // 8 floats / 8 shorts per lane
#pragma unroll 4
  for (int it = 0; it < 8; ++it) {
    int row = it * 8 + rg2;
    size_t goff = (size_t)(brow0 + row) * 256 + c8;
    f32x4 xa = nt_load_f4(x + goff);
    f32x4 xb = nt_load_f4(x + goff + 4);
    s16x8 rv = *(const s16x8*)(big + goff);
    s16x8 sv = *(const s16x8*)(swl + row * 264 + c8);
    s16x8 h;
#pragma unroll
    for (int j = 0; j < 4; ++j) {
      float xf = xa[j];
      h[j] = f2bf(xf + bf2f(sv[j]) * (xf - bf2f(rv[j])));
    }
#pragma unroll
    for (int j = 0; j < 4; ++j) {
      float xf = xb[j];
      h[4 + j] = f2bf(xf + bf2f(sv[4 + j]) * (xf - bf2f(rv[4 + j])));
    }
    *(s16x8*)(swl + row * 264 + c8) = h;
  }
  __syncthreads();

  // ---- phase 3: t = x2 @ Wlin^T ; wave w owns cols [w*64, w*64+64), all 64 rows ----
  f32x4 acc[16];
#pragma unroll
  for (int n = 0; n < 16; ++n) acc[n] = zero;
#pragma unroll
  for (int ksl = 0; ksl < 8; ++ksl) {
    if (ksl < 7) {
#pragma unroll
      for (int np = 0; np < 4; ++np)
        bf1[np] = *(const s16x8*)(Wlb2 + (size_t)(ksl + 1) * 8192 + (w * 4 + np) * 512 + l * 8);
    }
#pragma unroll
    for (int rg = 0; rg < 4; ++rg) {
      s16x8 a = *(const s16x8*)(swl + (rg * 16 + l15) * 264 + ksl * 32 + kg * 8);
#pragma unroll
      for (int np = 0; np < 4; ++np)
        acc[rg * 4 + np] = mfma16(a, bf0[np], acc[rg * 4 + np]);
    }
#pragma unroll
    for (int np = 0; np < 4; ++np) bf0[np] = bf1[np];
  }
  __syncthreads();  // all waves done reading swl

  // ---- stage t (bf16) into swl; stats into ls ----
#pragma unroll
  for (int rg = 0; rg < 4; ++rg)
#pragma unroll
    for (int r = 0; r < 4; ++r) {
      int row = rg * 16 + kg * 4 + r;
#pragma unroll
      for (int np = 0; np < 4; ++np)
        swl[row * 264 + (w * 4 + np) * 16 + l15] = f2bf(acc[rg * 4 + np][r]);
    }
#pragma unroll
  for (int np = 0; np < 4; ++np) {
    float sY = 0.f, sQ = 0.f;
#pragma unroll
    for (int rg = 0; rg < 4; ++rg)
#pragma unroll
      for (int r = 0; r < 4; ++r) {
        float v = acc[rg * 4 + np][r];
        sY += v;
        sQ += v * v;
      }
    sY += __shfl_xor(sY, 16); sY += __shfl_xor(sY, 32);
    sQ += __shfl_xor(sQ, 16); sQ += __shfl_xor(sQ, 32);
    if (l < 16) {
      ls[(w * 4 + np) * 16 + l15] = sY;
      ls[256 + (w * 4 + np) * 16 + l15] = sQ;
    }
  }
  __syncthreads();

  // ---- coalesced t write (16B per lane) + slotted stat atomics ----
  {
    int srow = t >> 2, sseg = (t & 3) * 64;
    const short* src = swl + srow * 264 + sseg;
    short* dst = big + (size_t)(brow0 + srow) * 256 + sseg;
#pragma unroll
    for (int j = 0; j < 8; ++j)
      *(s16x8*)(dst + j * 8) = *(const s16x8*)(src + j * 8);
  }
  float* slot = sum_t + (size_t)(blockIdx.x & (NSLOT_T - 1)) * 512;
  atomicAdd(&slot[t], ls[t]);
  atomicAdd(&slot[256 + t], ls[256 + t]);
}

// ---------------- k_out: out = relu(BN_main(t)); nt loads, regular stores ----------------
__global__ __launch_bounds__(256) void k_out(
    const short* __restrict__ tbuf, const float* __restrict__ sc_m,
    const float* __restrict__ sh_m, float* __restrict__ out) {
  __shared__ float lsc[256];
  __shared__ float lsh[256];
  int t = threadIdx.x;
  lsc[t] = sc_m[t];
  lsh[t] = sh_m[t];
  __syncthreads();
  int u0 = blockIdx.x * 256 + t;
#pragma unroll 2
  for (int it = 0; it < 8; ++it) {
    int u = u0 + it * (2048 * 256);     // 16-short groups
    int c16 = (u & 15) * 16;
    s16x8 tv0 = nt_load_s8(tbuf + (size_t)u * 16);
    s16x8 tv1 = nt_load_s8(tbuf + (size_t)u * 16 + 8);
    float4 o[4];
#pragma unroll
    for (int q = 0; q < 4; ++q) {
      float4 sc = *(const float4*)(lsc + c16 + q * 4);
      float4 sh = *(const float4*)(lsh + c16 + q * 4);
      short e0 = (q < 2) ? tv0[(q & 1) * 4 + 0] : tv1[(q & 1) * 4 + 0];
      short e1 = (q < 2) ? tv0[(q & 1) * 4 + 1] : tv1[(q & 1) * 4 + 1];
      short e2 = (q < 2) ? tv0[(q & 1) * 4 + 2] : tv1[(q & 1) * 4 + 2];
      short e3 = (q < 2) ? tv0[(q & 1) * 4 + 3] : tv1[(q & 1) * 4 + 3];
      o[q].x = fmaxf(bf2f(e0) * sc.x + sh.x, 0.f);
      o[q].y = fmaxf(bf2f(e1) * sc.y + sh.y, 0.f);
      o[q].z = fmaxf(bf2f(e2) * sc.z + sh.z, 0.f);
      o[q].w = fmaxf(bf2f(e3) * sc.w + sh.w, 0.f);
    }
#pragma unroll
    for (int q = 0; q < 4; ++q)
      *(float4*)(out + (size_t)u * 16 + q * 4) = o[q];
  }
}

extern "C" void kernel_launch(void* const* d_in, const int* in_sizes, int n_in,
                              void* d_out, int out_size, void* d_ws, size_t ws_size,
                              hipStream_t stream) {
  const float* x      = (const float*)d_in[1];
  const float* gx     = (const float*)d_in[2];
  const int*   idx    = (const int*)d_in[3];
  const float* Wlin   = (const float*)d_in[4];
  const float* g_main = (const float*)d_in[5];
  const float* b_main = (const float*)d_in[6];
  const float* g_a    = (const float*)d_in[7];
  const float* b_a    = (const float*)d_in[8];
  const float* W1     = (const float*)d_in[9];
  // d_in[10] = b1 : cancels inside BN_b -> unused
  const float* g_b    = (const float*)d_in[11];
  const float* b_b    = (const float*)d_in[12];
  const float* W2     = (const float*)d_in[13];
  const float* b2     = (const float*)d_in[14];
  float* out = (float*)d_out;
  float* wsf = (float*)d_ws;

  // --- fixed small ws area (round-14 layout, proven) ---
  float* sum_b = wsf;                    // 16 slots x 64 = 1024 floats
  float* sc_a = wsf + 1024; float* sh_a = wsf + 1280;
  float* sc_b = wsf + 1536; float* sh_b = wsf + 1568;
  float* sc_m = wsf + 1600; float* sh_m = wsf + 1856;
  short* W1b  = (short*)(wsf + 2112);    // 8192 shorts
  short* W2b  = (short*)(wsf + 6208);    // 8192 shorts
  short* Wlb2 = (short*)(wsf + 10304);   // 65536 shorts -> ends at float off 43072

  // --- ws_size-derived tail (same as rounds 4-16) ---
  size_t big_off = (ws_size - (size_t)134217728) & ~(size_t)1023;
  size_t yh_off  = big_off - (size_t)16777216;
  short* big = (short*)((char*)d_ws + big_off);  // N*256 bf16 : rel -> t
  short* yh  = (short*)((char*)d_ws + yh_off);   // N*32 bf16

  // --- big stats buffers in d_out's tail (dead until k_out overwrites) ---
  float* sum_t = out + (size_t)N_PTS * 256 - 65536;  // 32768 floats
  float* sum_a = out + (size_t)N_PTS * 256 - 32768;  // 32768 floats

  k_init<<<385, 256, 0, stream>>>(wsf, sum_t, W1, W2, Wlin);
  k_rel<<<N_PTS / 64, 256, 0, stream>>>(x, gx, idx, big, sum_a);
  k_fin<<<1, 256, 0, stream>>>(sum_a, g_a, b_a, sc_a, sh_a, 256, 1.f / N_PTS, NSLOT_A);
  k_y<<<N_PTS / 64, 256, 0, stream>>>(big, W1b, sc_a, sh_a, yh, sum_b);
  k_fin<<<1, 64, 0, stream>>>(sum_b, g_b, b_b, sc_b, sh_b, 32, 1.f / N_PTS, NSLOT_B);
  k_x2g<<<N_PTS / 64, 256, 0, stream>>>(yh, W2b, b2, x, Wlb2, sc_b, sh_b, big, sum_t);
  k_fin<<<1, 256, 0, stream>>>(sum_t, g_main, b_main, sc_m, sh_m, 256, 1.f / N_PTS, NSLOT_T);
  k_out<<<2048, 256, 0, stream>>>(big, sc_m, sh_m, out);
}

// Round 18
// 465.401 us; speedup vs baseline: 1.0777x; 1.0777x over previous
//
#include <hip/hip_runtime.h>
#include <stdint.h>
#include <stddef.h>

#define N_PTS 262144
#define M_PTS 131072
#define C_DIM 256
#define H_DIM 32
#define EPS_BN 1e-5f
#define NSLOT_A 64
#define NSLOT_B 16
#define NSLOT_T 64

using s16x8 = __attribute__((ext_vector_type(8))) short;
using s16x4 = __attribute__((ext_vector_type(4))) short;
using f32x4 = __attribute__((ext_vector_type(4))) float;

__device__ __forceinline__ short f2bf(float f) {
  __bf16 h = (__bf16)f;
  return __builtin_bit_cast(short, h);
}
__device__ __forceinline__ float bf2f(short s) {
  unsigned int u = ((unsigned int)(unsigned short)s) << 16;
  return __builtin_bit_cast(float, u);
}
__device__ __forceinline__ f32x4 mfma16(s16x8 a, s16x8 b, f32x4 c) {
  return __builtin_amdgcn_mfma_f32_16x16x32_bf16(a, b, c, 0, 0, 0);
}
__device__ __forceinline__ f32x4 nt_load_f4(const float* p) {
  return __builtin_nontemporal_load((const f32x4*)p);
}
__device__ __forceinline__ s16x8 nt_load_s8(const short* p) {
  return __builtin_nontemporal_load((const s16x8*)p);
}

// ---------------- k_init: zero stats, convert weights to bf16 (1 launch) ----------------
__global__ __launch_bounds__(256) void k_init(
    float* __restrict__ wsf, float* __restrict__ sum_t,
    const float* __restrict__ W1, const float* __restrict__ W2,
    const float* __restrict__ Wlin) {
  int t = threadIdx.x, b = blockIdx.x;
  f32x4 z = {0.f, 0.f, 0.f, 0.f};
  if (b == 0) {
    *(f32x4*)(wsf + t * 4) = z;                 // sum_b (1024 floats)
  } else if (b <= 64) {
    *(f32x4*)(sum_t + (size_t)((b - 1) * 256 + t) * 4) = z;  // sum_t|sum_a (65536)
  } else {
    int i = (b - 65) * 256 + t;                 // 81920 prep threads
    short* W1b  = (short*)(wsf + 2112);
    short* W2b  = (short*)(wsf + 6208);
    short* Wlb2 = (short*)(wsf + 10304);
    if (i < 8192) {
      W1b[i] = f2bf(W1[i]);
    } else if (i < 16384) {
      W2b[i - 8192] = f2bf(W2[i - 8192]);
    } else {
      int s = i - 16384;
      int col = s >> 8, k = s & 255;
      int ksl = k >> 5, kg = (k >> 3) & 3, e = k & 7;
      int n = col >> 4, cl = col & 15;
      Wlb2[ksl * 8192 + n * 512 + kg * 128 + cl * 8 + e] = f2bf(Wlin[s]);
    }
  }
}

// ---------------- k_rel: rel = x - gx[idx] (bf16, 16B stores) + BN_a stats ----------------
__global__ __launch_bounds__(256) void k_rel(
    const float* __restrict__ x, const float* __restrict__ gx,
    const int* __restrict__ idx, short* __restrict__ rel,
    float* __restrict__ sum_a) {
  __shared__ int lidx[64];
  __shared__ float redS[8][264];
  __shared__ float redQ[8][264];
  int t = threadIdx.x;
  int rg = t >> 5;          // row-group 0..7 (8 rows per iteration)
  int c8 = (t & 31) * 8;    // column start (8 floats/shorts per lane)
  int brow = blockIdx.x * 64;
  if (t < 64) lidx[t] = idx[brow + t];
  __syncthreads();

  float s[8] = {0, 0, 0, 0, 0, 0, 0, 0};
  float q[8] = {0, 0, 0, 0, 0, 0, 0, 0};
#pragma unroll 4
  for (int it = 0; it < 8; ++it) {
    int rl = it * 8 + rg;
    int ir = lidx[rl];
    const float* xr = x + (size_t)(brow + rl) * 256 + c8;
    const float* gr = gx + (size_t)ir * 256 + c8;
    f32x4 xa = nt_load_f4(xr);
    f32x4 xb = nt_load_f4(xr + 4);
    float4 ga = *(const float4*)(gr);
    float4 gb = *(const float4*)(gr + 4);
    float d0 = xa[0] - ga.x, d1 = xa[1] - ga.y, d2 = xa[2] - ga.z, d3 = xa[3] - ga.w;
    float d4 = xb[0] - gb.x, d5 = xb[1] - gb.y, d6 = xb[2] - gb.z, d7 = xb[3] - gb.w;
    s16x8 h;
    h[0] = f2bf(d0); h[1] = f2bf(d1); h[2] = f2bf(d2); h[3] = f2bf(d3);
    h[4] = f2bf(d4); h[5] = f2bf(d5); h[6] = f2bf(d6); h[7] = f2bf(d7);
    *(s16x8*)(rel + (size_t)(brow + rl) * 256 + c8) = h;
    s[0] += d0; s[1] += d1; s[2] += d2; s[3] += d3;
    s[4] += d4; s[5] += d5; s[6] += d6; s[7] += d7;
    q[0] += d0 * d0; q[1] += d1 * d1; q[2] += d2 * d2; q[3] += d3 * d3;
    q[4] += d4 * d4; q[5] += d5 * d5; q[6] += d6 * d6; q[7] += d7 * d7;
  }
#pragma unroll
  for (int j = 0; j < 8; ++j) {
    redS[rg][c8 + j] = s[j];
    redQ[rg][c8 + j] = q[j];
  }
  __syncthreads();
  float vs = 0.f, vq = 0.f;
#pragma unroll
  for (int g = 0; g < 8; ++g) {
    vs += redS[g][t];
    vq += redQ[g][t];
  }
  float* slot = sum_a + (size_t)(blockIdx.x & (NSLOT_A - 1)) * 512;
  atomicAdd(&slot[t], vs);
  atomicAdd(&slot[256 + t], vq);
}

// ---------------- k_fin: slotted sums -> scale/shift ----------------
__global__ void k_fin(const float* __restrict__ sums, const float* __restrict__ g,
                      const float* __restrict__ b, float* __restrict__ sc,
                      float* __restrict__ sh, int n, float invN, int nslot) {
  int c = threadIdx.x;
  if (c < n) {
    float S = 0.f, Q = 0.f;
    for (int s = 0; s < nslot; ++s) {
      S += sums[(size_t)s * 2 * n + c];
      Q += sums[(size_t)s * 2 * n + n + c];
    }
    float mu = S * invN;
    float var = Q * invN - mu * mu;
    float rs = rsqrtf(var + EPS_BN);
    float scale = g[c] * rs;
    sc[c] = scale;
    sh[c] = b[c] - mu * scale;
  }
}

// ---------------- k_y: y = relu(BN_a(rel)) @ W1^T ; y bf16 + stats ----------------
__global__ __launch_bounds__(256) void k_y(
    const short* __restrict__ rel, const short* __restrict__ W1b,
    const float* __restrict__ sc_a, const float* __restrict__ sh_a,
    short* __restrict__ yh, float* __restrict__ sum_b) {
  __shared__ __attribute__((aligned(16))) short Ab[64 * 264];
  __shared__ float lsc[256];
  __shared__ float lsh[256];
  __shared__ float red[4][64];
  int t = threadIdx.x;
  lsc[t] = sc_a[t];
  lsh[t] = sh_a[t];
  {
    int srow = t >> 2, sseg = (t & 3) * 64;
    const short* src = rel + (size_t)(blockIdx.x * 64 + srow) * 256 + sseg;
    short* dst = Ab + srow * 264 + sseg;
#pragma unroll
    for (int j = 0; j < 8; ++j)
      *(s16x8*)(dst + j * 8) = *(const s16x8*)(src + j * 8);
  }
  __syncthreads();
  int w = t >> 6, l = t & 63, l15 = l & 15, kg = l >> 4;
  int r0 = blockIdx.x * 64 + w * 16;
  const short* arow = Ab + (w * 16 + l15) * 264;

  s16x8 bfr[2][8];
#pragma unroll
  for (int j = 0; j < 2; ++j)
#pragma unroll
    for (int kk = 0; kk < 8; ++kk)
      bfr[j][kk] = *(const s16x8*)(W1b + (j * 16 + l15) * 256 + kg * 8 + kk * 32);

  f32x4 acc0 = {0.f, 0.f, 0.f, 0.f};
  f32x4 acc1 = {0.f, 0.f, 0.f, 0.f};
#pragma unroll
  for (int kk = 0; kk < 8; ++kk) {
    int k0 = kg * 8 + kk * 32;
    s16x8 a = *(const s16x8*)(arow + k0);
    s16x8 af;
#pragma unroll
    for (int i = 0; i < 8; ++i) {
      float v = bf2f(a[i]);
      v = fmaxf(v * lsc[k0 + i] + lsh[k0 + i], 0.f);
      af[i] = f2bf(v);
    }
    acc0 = mfma16(af, bfr[0][kk], acc0);
    acc1 = mfma16(af, bfr[1][kk], acc1);
  }

  float s0 = 0.f, q0 = 0.f, s1 = 0.f, q1 = 0.f;
#pragma unroll
  for (int reg = 0; reg < 4; ++reg) {
    int gr = r0 + kg * 4 + reg;
    float y0 = acc0[reg], y1 = acc1[reg];
    yh[(size_t)gr * 32 + l15] = f2bf(y0);
    yh[(size_t)gr * 32 + 16 + l15] = f2bf(y1);
    s0 += y0; q0 += y0 * y0;
    s1 += y1; q1 += y1 * y1;
  }
  s0 += __shfl_xor(s0, 16); s0 += __shfl_xor(s0, 32);
  q0 += __shfl_xor(q0, 16); q0 += __shfl_xor(q0, 32);
  s1 += __shfl_xor(s1, 16); s1 += __shfl_xor(s1, 32);
  q1 += __shfl_xor(q1, 16); q1 += __shfl_xor(q1, 32);
  if (l < 16) {
    red[w][l15] = s0;
    red[w][16 + l15] = s1;
    red[w][32 + l15] = q0;
    red[w][48 + l15] = q1;
  }
  __syncthreads();
  if (t < 64) {
    float v = red[0][t] + red[1][t] + red[2][t] + red[3][t];
    atomicAdd(&sum_b[(size_t)(blockIdx.x & (NSLOT_B - 1)) * 64 + t], v);
  }
}

// ---------------- k_x2g: z GEMM + softmax + combine + Wlin GEMM ----------------
// Phase 3: wave-per-column-group, B direct from L2 (depth-2 prefetch), no barriers.
// x read non-temporal. Epilogue: t staged through swl for coalesced 16B stores.
__global__ __launch_bounds__(256) void k_x2g(
    const short* __restrict__ yh, const short* __restrict__ W2b,
    const float* __restrict__ b2, const float* __restrict__ x,
    const short* __restrict__ Wlb2, const float* __restrict__ sc_b,
    const float* __restrict__ sh_b, short* __restrict__ big,
    float* __restrict__ sum_t) {
  __shared__ __attribute__((aligned(16))) short swl[64 * 264];  // 33792 B
  __shared__ float ls[512];                                     // 2048 B
  int t = threadIdx.x, w = t >> 6, l = t & 63, l15 = l & 15, kg = l >> 4;
  int r0 = blockIdx.x * 64 + w * 16;
  int lr = r0 + l15;

  // ---- phase 1: z = relu(BN_b(y)) @ W2^T + b2 ; row-softmax -> sw (LDS bf16) ----
  s16x8 yb = *(const s16x8*)(yh + (size_t)lr * 32 + kg * 8);
  s16x8 af;
#pragma unroll
  for (int i = 0; i < 8; ++i) {
    int k = kg * 8 + i;
    float v = bf2f(yb[i]);
    v = fmaxf(v * sc_b[k] + sh_b[k], 0.f);
    af[i] = f2bf(v);
  }
  f32x4 zero = {0.f, 0.f, 0.f, 0.f};
  f32x4 z[16];
#pragma unroll
  for (int n = 0; n < 16; ++n) {
    s16x8 bf = *(const s16x8*)(W2b + (n * 16 + l15) * 32 + kg * 8);
    z[n] = mfma16(af, bf, zero);
  }
  float b2c[16];
#pragma unroll
  for (int n = 0; n < 16; ++n) b2c[n] = b2[n * 16 + l15];
  float mx[4] = {-3.4e38f, -3.4e38f, -3.4e38f, -3.4e38f};
#pragma unroll
  for (int n = 0; n < 16; ++n)
#pragma unroll
    for (int r = 0; r < 4; ++r) {
      z[n][r] += b2c[n];
      mx[r] = fmaxf(mx[r], z[n][r]);
    }
#pragma unroll
  for (int r = 0; r < 4; ++r) {
    mx[r] = fmaxf(mx[r], __shfl_xor(mx[r], 1));
    mx[r] = fmaxf(mx[r], __shfl_xor(mx[r], 2));
    mx[r] = fmaxf(mx[r], __shfl_xor(mx[r], 4));
    mx[r] = fmaxf(mx[r], __shfl_xor(mx[r], 8));
  }
  float sm[4] = {0.f, 0.f, 0.f, 0.f};
#pragma unroll
  for (int n = 0; n < 16; ++n)
#pragma unroll
    for (int r = 0; r < 4; ++r) {
      float e = __expf(z[n][r] - mx[r]);
      z[n][r] = e;
      sm[r] += e;
    }
#pragma unroll
  for (int r = 0; r < 4; ++r) {
    sm[r] += __shfl_xor(sm[r], 1);
    sm[r] += __shfl_xor(sm[r], 2);
    sm[r] += __shfl_xor(sm[r], 4);
    sm[r] += __shfl_xor(sm[r], 8);
    sm[r] = 1.f / sm[r];
  }
#pragma unroll
  for (int n = 0; n < 16; ++n)
#pragma unroll
    for (int r = 0; r < 4; ++r)
      swl[(w * 16 + kg * 4 + r) * 264 + n * 16 + l15] = f2bf(z[n][r] * sm[r]);
  __syncthreads();

  // ---- early-issue B fragments for ksl=0 (latency hides under phase 2) ----
  s16x8 bf0[4], bf1[4];
#pragma unroll
  for (int np = 0; np < 4; ++np)
    bf0[np] = *(const s16x8*)(Wlb2 + (w * 4 + np) * 512 + l * 8);

  // ---- phase 2: combine in place: swl[row][col] <- x2 = x + sw*(x - rel) ----
  int brow0 = blockIdx.x * 64;
  int c4 = (t & 63) * 4;
#pragma unroll 4
  for (int it = 0; it < 16; ++it) {
    int row = it * 4 + w;
    size_t goff = (size_t)(brow0 + row) * 256 + c4;
    f32x4 xv = nt_load_f4(x + goff);
    s16x4 rv = *(const s16x4*)(big + goff);
    s16x4 sv = *(const s16x4*)(swl + row * 264 + c4);
    s16x4 h;
#pragma unroll
    for (int j = 0; j < 4; ++j) {
      float xf = xv[j];
      float aug = xf - bf2f(rv[j]);
      h[j] = f2bf(xf + bf2f(sv[j]) * aug);
    }
    *(s16x4*)(swl + row * 264 + c4) = h;
  }
  __syncthreads();

  // ---- phase 3: t = x2 @ Wlin^T ; wave w owns cols [w*64, w*64+64), all 64 rows ----
  f32x4 acc[16];
#pragma unroll
  for (int n = 0; n < 16; ++n) acc[n] = zero;
#pragma unroll
  for (int ksl = 0; ksl < 8; ++ksl) {
    if (ksl < 7) {
#pragma unroll
      for (int np = 0; np < 4; ++np)
        bf1[np] = *(const s16x8*)(Wlb2 + (size_t)(ksl + 1) * 8192 + (w * 4 + np) * 512 + l * 8);
    }
#pragma unroll
    for (int rg = 0; rg < 4; ++rg) {
      s16x8 a = *(const s16x8*)(swl + (rg * 16 + l15) * 264 + ksl * 32 + kg * 8);
#pragma unroll
      for (int np = 0; np < 4; ++np)
        acc[rg * 4 + np] = mfma16(a, bf0[np], acc[rg * 4 + np]);
    }
#pragma unroll
    for (int np = 0; np < 4; ++np) bf0[np] = bf1[np];
  }
  __syncthreads();  // all waves done reading swl

  // ---- stage t (bf16) into swl; stats into ls ----
#pragma unroll
  for (int rg = 0; rg < 4; ++rg)
#pragma unroll
    for (int r = 0; r < 4; ++r) {
      int row = rg * 16 + kg * 4 + r;
#pragma unroll
      for (int np = 0; np < 4; ++np)
        swl[row * 264 + (w * 4 + np) * 16 + l15] = f2bf(acc[rg * 4 + np][r]);
    }
#pragma unroll
  for (int np = 0; np < 4; ++np) {
    float sY = 0.f, sQ = 0.f;
#pragma unroll
    for (int rg = 0; rg < 4; ++rg)
#pragma unroll
      for (int r = 0; r < 4; ++r) {
        float v = acc[rg * 4 + np][r];
        sY += v;
        sQ += v * v;
      }
    sY += __shfl_xor(sY, 16); sY += __shfl_xor(sY, 32);
    sQ += __shfl_xor(sQ, 16); sQ += __shfl_xor(sQ, 32);
    if (l < 16) {
      ls[(w * 4 + np) * 16 + l15] = sY;
      ls[256 + (w * 4 + np) * 16 + l15] = sQ;
    }
  }
  __syncthreads();

  // ---- coalesced t write (16B per lane) + slotted stat atomics ----
  {
    int srow = t >> 2, sseg = (t & 3) * 64;
    const short* src = swl + srow * 264 + sseg;
    short* dst = big + (size_t)(brow0 + srow) * 256 + sseg;
#pragma unroll
    for (int j = 0; j < 8; ++j)
      *(s16x8*)(dst + j * 8) = *(const s16x8*)(src + j * 8);
  }
  float* slot = sum_t + (size_t)(blockIdx.x & (NSLOT_T - 1)) * 512;
  atomicAdd(&slot[t], ls[t]);
  atomicAdd(&slot[256 + t], ls[256 + t]);
}

// ---------------- k_out: out = relu(BN_main(t)); nt loads, regular stores ----------------
__global__ __launch_bounds__(256) void k_out(
    const short* __restrict__ tbuf, const float* __restrict__ sc_m,
    const float* __restrict__ sh_m, float* __restrict__ out) {
  __shared__ float lsc[256];
  __shared__ float lsh[256];
  int t = threadIdx.x;
  lsc[t] = sc_m[t];
  lsh[t] = sh_m[t];
  __syncthreads();
  int u0 = blockIdx.x * 256 + t;
#pragma unroll 2
  for (int it = 0; it < 8; ++it) {
    int u = u0 + it * (2048 * 256);     // 16-short groups
    int c16 = (u & 15) * 16;
    s16x8 tv0 = nt_load_s8(tbuf + (size_t)u * 16);
    s16x8 tv1 = nt_load_s8(tbuf + (size_t)u * 16 + 8);
    float4 o[4];
#pragma unroll
    for (int q = 0; q < 4; ++q) {
      float4 sc = *(const float4*)(lsc + c16 + q * 4);
      float4 sh = *(const float4*)(lsh + c16 + q * 4);
      short e0 = (q < 2) ? tv0[(q & 1) * 4 + 0] : tv1[(q & 1) * 4 + 0];
      short e1 = (q < 2) ? tv0[(q & 1) * 4 + 1] : tv1[(q & 1) * 4 + 1];
      short e2 = (q < 2) ? tv0[(q & 1) * 4 + 2] : tv1[(q & 1) * 4 + 2];
      short e3 = (q < 2) ? tv0[(q & 1) * 4 + 3] : tv1[(q & 1) * 4 + 3];
      o[q].x = fmaxf(bf2f(e0) * sc.x + sh.x, 0.f);
      o[q].y = fmaxf(bf2f(e1) * sc.y + sh.y, 0.f);
      o[q].z = fmaxf(bf2f(e2) * sc.z + sh.z, 0.f);
      o[q].w = fmaxf(bf2f(e3) * sc.w + sh.w, 0.f);
    }
#pragma unroll
    for (int q = 0; q < 4; ++q)
      *(float4*)(out + (size_t)u * 16 + q * 4) = o[q];
  }
}

extern "C" void kernel_launch(void* const* d_in, const int* in_sizes, int n_in,
                              void* d_out, int out_size, void* d_ws, size_t ws_size,
                              hipStream_t stream) {
  const float* x      = (const float*)d_in[1];
  const float* gx     = (const float*)d_in[2];
  const int*   idx    = (const int*)d_in[3];
  const float* Wlin   = (const float*)d_in[4];
  const float* g_main = (const float*)d_in[5];
  const float* b_main = (const float*)d_in[6];
  const float* g_a    = (const float*)d_in[7];
  const float* b_a    = (const float*)d_in[8];
  const float* W1     = (const float*)d_in[9];
  // d_in[10] = b1 : cancels inside BN_b -> unused
  const float* g_b    = (const float*)d_in[11];
  const float* b_b    = (const float*)d_in[12];
  const float* W2     = (const float*)d_in[13];
  const float* b2     = (const float*)d_in[14];
  float* out = (float*)d_out;
  float* wsf = (float*)d_ws;

  // --- fixed small ws area (round-14 layout, proven) ---
  float* sum_b = wsf;                    // 16 slots x 64 = 1024 floats
  float* sc_a = wsf + 1024; float* sh_a = wsf + 1280;
  float* sc_b = wsf + 1536; float* sh_b = wsf + 1568;
  float* sc_m = wsf + 1600; float* sh_m = wsf + 1856;
  short* W1b  = (short*)(wsf + 2112);    // 8192 shorts
  short* W2b  = (short*)(wsf + 6208);    // 8192 shorts
  short* Wlb2 = (short*)(wsf + 10304);   // 65536 shorts -> ends at float off 43072

  // --- ws_size-derived tail (same as rounds 4-17) ---
  size_t big_off = (ws_size - (size_t)134217728) & ~(size_t)1023;
  size_t yh_off  = big_off - (size_t)16777216;
  short* big = (short*)((char*)d_ws + big_off);  // N*256 bf16 : rel -> t
  short* yh  = (short*)((char*)d_ws + yh_off);   // N*32 bf16

  // --- big stats buffers in d_out's tail (dead until k_out overwrites) ---
  float* sum_t = out + (size_t)N_PTS * 256 - 65536;  // 32768 floats
  float* sum_a = out + (size_t)N_PTS * 256 - 32768;  // 32768 floats

  k_init<<<385, 256, 0, stream>>>(wsf, sum_t, W1, W2, Wlin);
  k_rel<<<N_PTS / 64, 256, 0, stream>>>(x, gx, idx, big, sum_a);
  k_fin<<<1, 256, 0, stream>>>(sum_a, g_a, b_a, sc_a, sh_a, 256, 1.f / N_PTS, NSLOT_A);
  k_y<<<N_PTS / 64, 256, 0, stream>>>(big, W1b, sc_a, sh_a, yh, sum_b);
  k_fin<<<1, 64, 0, stream>>>(sum_b, g_b, b_b, sc_b, sh_b, 32, 1.f / N_PTS, NSLOT_B);
  k_x2g<<<N_PTS / 64, 256, 0, stream>>>(yh, W2b, b2, x, Wlb2, sc_b, sh_b, big, sum_t);
  k_fin<<<1, 256, 0, stream>>>(sum_t, g_main, b_main, sc_m, sh_m, 256, 1.f / N_PTS, NSLOT_T);
  k_out<<<2048, 256, 0, stream>>>(big, sc_m, sh_m, out);
}